// Round 8
// baseline (311.733 us; speedup 1.0000x reference)
//
#include <hip/hip_runtime.h>

#define L_NODES 100000
#define NFEAT   256
#define JDIM    128

typedef __bf16 bf16x8 __attribute__((ext_vector_type(8)));
typedef __bf16 bf16x4 __attribute__((ext_vector_type(4)));
typedef float  floatx4 __attribute__((ext_vector_type(4)));

// ---------------------------------------------------------------------------
// Prep (single launch, into d_ws weight region — NOT d_out: k_final2 writes
// d_out concurrently with weight reads, which raced in R7):
//   WtH[n][k]  = bf16(W_h1[k][n])        n,k in [0,128)x[0,256)
//   WtGu[n][k] = bf16(W_g1[k][n])        n,k in [0,128)x[0,256)
//   WtGb[n][k] = bf16(W_g1[128+k][n])    n,k in [0,128)x[0,128)
// ---------------------------------------------------------------------------
__global__ __launch_bounds__(256) void k_prep(
    const float* __restrict__ Wh, const float* __restrict__ Wg,
    __bf16* __restrict__ WtH, __bf16* __restrict__ WtGu,
    __bf16* __restrict__ WtGb)
{
    int i = blockIdx.x * 256 + threadIdx.x;   // 32768
    int n = i >> 8, k = i & 255;
    WtH[i]  = (__bf16)Wh[k * JDIM + n];
    WtGu[i] = (__bf16)Wg[k * JDIM + n];
    if (i < 16384) {
        int n2 = i >> 7, k2 = i & 127;
        WtGb[i] = (__bf16)Wg[(128 + k2) * JDIM + n2];
    }
}

// ---------------------------------------------------------------------------
// Kernel 1 (fused, MFMA): H = relu(X @ W_h1 + b) kept in LDS, then
// U = H @ Wg[0:128,:], V = H @ Wg[128:,:] written to global. H never
// materialized in HBM (final2 uses U instead of H).
// Phase 1: R3-proven 128x128 H-tile, waves (mh,wc) = 4m x 4n tiles.
// Phase 2: waves (wm,wn) = 4 m-tiles x 8 n-tiles over N=256 (U||V),
//          A-frags from LDS, output staged through LDS in two column-halves.
// ---------------------------------------------------------------------------
__global__ __launch_bounds__(256) void k_h1uv(
    const float* __restrict__ X, const __bf16* __restrict__ WtH,
    const __bf16* __restrict__ WtGu, const float* __restrict__ b,
    __bf16* __restrict__ U, __bf16* __restrict__ V)
{
    __shared__ __bf16 As[128][136];

    const int tid  = threadIdx.x;
    const int row0 = blockIdx.x * 128;
    const int wave = tid >> 6, lane = tid & 63;
    const int lm = lane & 15, lq = lane >> 4;

    // ---- phase 1: H tile ----
    {
        const int mh = wave >> 1, wc = wave & 1;
        const __bf16* bptr[4];
        #pragma unroll
        for (int nt = 0; nt < 4; ++nt)
            bptr[nt] = WtH + (size_t)(wc * 64 + nt * 16 + lm) * 256 + lq * 8;

        floatx4 acc[4][4] = {};
        bf16x8 bc[4], bn[4];
        #pragma unroll
        for (int nt = 0; nt < 4; ++nt) bc[nt] = *(const bf16x8*)bptr[nt];

        for (int half = 0; half < 2; ++half) {
            #pragma unroll
            for (int it = 0; it < 16; ++it) {
                int f4  = it * 256 + tid;
                int row = f4 >> 5;
                int c4  = f4 & 31;
                int grow = row0 + row; if (grow >= L_NODES) grow = L_NODES - 1;
                float4 v = *(const float4*)(X + (size_t)grow * NFEAT + half * 128 + c4 * 4);
                bf16x4 o; o[0]=(__bf16)v.x; o[1]=(__bf16)v.y; o[2]=(__bf16)v.z; o[3]=(__bf16)v.w;
                *(bf16x4*)&As[row][c4 * 4] = o;
            }
            __syncthreads();
            #pragma unroll
            for (int ksl = 0; ksl < 4; ++ksl) {
                int ks = half * 4 + ksl;
                if (ks < 7)
                    #pragma unroll
                    for (int nt = 0; nt < 4; ++nt)
                        bn[nt] = *(const bf16x8*)(bptr[nt] + (ks + 1) * 32);
                bf16x8 af[4];
                #pragma unroll
                for (int t = 0; t < 4; ++t)
                    af[t] = *(const bf16x8*)&As[mh * 64 + t * 16 + lm][ksl * 32 + lq * 8];
                #pragma unroll
                for (int t = 0; t < 4; ++t)
                    #pragma unroll
                    for (int nt = 0; nt < 4; ++nt)
                        acc[t][nt] = __builtin_amdgcn_mfma_f32_16x16x32_bf16(
                            af[t], bc[nt], acc[t][nt], 0, 0, 0);
                #pragma unroll
                for (int nt = 0; nt < 4; ++nt) bc[nt] = bn[nt];
            }
            __syncthreads();
        }

        // H (bias+relu, bf16) -> LDS
        #pragma unroll
        for (int nt = 0; nt < 4; ++nt) {
            int col = wc * 64 + nt * 16 + lm;
            float bias = b[col];
            #pragma unroll
            for (int t = 0; t < 4; ++t)
                #pragma unroll
                for (int p = 0; p < 4; ++p)
                    As[mh * 64 + t * 16 + lq * 4 + p][col] =
                        (__bf16)fmaxf(acc[t][nt][p] + bias, 0.f);
        }
        __syncthreads();
    }

    // ---- phase 2: U||V = H @ WgU||WgV  (K=128, N=256) ----
    const int wm = wave >> 1, wn = wave & 1;
    // output col c = wn*128 + nt*16 + lm; B row n = c & 127, k = wn*128 + kk
    const __bf16* bbase = WtGu + (size_t)lm * 256 + wn * 128 + lq * 8;

    floatx4 acc2[4][8] = {};
    bf16x8 bc2[8], bn2[8];
    #pragma unroll
    for (int nt = 0; nt < 8; ++nt)
        bc2[nt] = *(const bf16x8*)(bbase + (size_t)nt * 16 * 256);

    #pragma unroll
    for (int ks = 0; ks < 4; ++ks) {
        if (ks < 3)
            #pragma unroll
            for (int nt = 0; nt < 8; ++nt)
                bn2[nt] = *(const bf16x8*)(bbase + (size_t)nt * 16 * 256 + (ks + 1) * 32);
        bf16x8 af[4];
        #pragma unroll
        for (int t = 0; t < 4; ++t)
            af[t] = *(const bf16x8*)&As[wm * 64 + t * 16 + lm][ks * 32 + lq * 8];
        #pragma unroll
        for (int t = 0; t < 4; ++t)
            #pragma unroll
            for (int nt = 0; nt < 8; ++nt)
                acc2[t][nt] = __builtin_amdgcn_mfma_f32_16x16x32_bf16(
                    af[t], bc2[nt], acc2[t][nt], 0, 0, 0);
        #pragma unroll
        for (int nt = 0; nt < 8; ++nt) bc2[nt] = bn2[nt];
    }
    __syncthreads();   // all LDS H reads done

    // stage + store U (cols 0..127), then V (cols 128..255)
    #pragma unroll
    for (int hf = 0; hf < 2; ++hf) {
        if (wn == hf) {
            #pragma unroll
            for (int nt = 0; nt < 8; ++nt) {
                int col = nt * 16 + lm;
                #pragma unroll
                for (int t = 0; t < 4; ++t)
                    #pragma unroll
                    for (int p = 0; p < 4; ++p)
                        As[wm * 64 + t * 16 + lq * 4 + p][col] = (__bf16)acc2[t][nt][p];
            }
        }
        __syncthreads();
        __bf16* dst = hf ? V : U;
        #pragma unroll
        for (int it = 0; it < 8; ++it) {
            int fid = it * 256 + tid;
            int row = fid >> 4, fr = fid & 15;
            int grow = row0 + row;
            if (grow < L_NODES)
                *(bf16x8*)(dst + (size_t)grow * JDIM + fr * 8) = *(bf16x8*)&As[row][fr * 8];
        }
        __syncthreads();
    }
}

// ---------------------------------------------------------------------------
// Kernel 2 (gather-add): E1b[i] = bf16(relu(mean_s relu(U[idx0]+V[idx1]+b)))
// R5-proven config: 16 nodes/block, 1 node/thread, 16 independent loads.
// Random-BW bound (~6.6 TB/s delivered) — measured floor ~61 us.
// ---------------------------------------------------------------------------
__global__ __launch_bounds__(256) void k_gather(
    const __bf16* __restrict__ U, const __bf16* __restrict__ V,
    const float* __restrict__ b,
    const int* __restrict__ idx0, const int* __restrict__ idx1,
    __bf16* __restrict__ E1b)
{
    __shared__ int s0[8][16], s1[8][16];

    const int tid = threadIdx.x;
    const int i0  = blockIdx.x * 16;

    if (tid < 128) {
        int s = tid >> 4, il = tid & 15;
        s0[s][il] = idx0[(size_t)s * L_NODES + i0 + il];
    } else {
        int t = tid - 128, s = t >> 4, il = t & 15;
        s1[s][il] = idx1[(size_t)s * L_NODES + i0 + il];
    }
    __syncthreads();

    const int il = tid >> 4;
    const int c0 = (tid & 15) * 8;

    float bias[8];
    *(float4*)&bias[0] = *(const float4*)(b + c0);
    *(float4*)&bias[4] = *(const float4*)(b + c0 + 4);

    float acc[8] = {};
    #pragma unroll
    for (int s = 0; s < 8; ++s) {
        int r0 = s0[s][il], r1 = s1[s][il];
        bf16x8 u = *(const bf16x8*)(U + (size_t)r0 * JDIM + c0);
        bf16x8 v = *(const bf16x8*)(V + (size_t)r1 * JDIM + c0);
        #pragma unroll
        for (int p = 0; p < 8; ++p)
            acc[p] += fmaxf((float)u[p] + (float)v[p] + bias[p], 0.f);
    }

    bf16x8 o;
    #pragma unroll
    for (int p = 0; p < 8; ++p)
        o[p] = (__bf16)fmaxf(acc[p] * 0.125f, 0.f);
    *(bf16x8*)(E1b + (size_t)(i0 + il) * JDIM + c0) = o;
}

// ---------------------------------------------------------------------------
// Kernel 3 (MFMA, K=128): E2 = relu(U + E1b @ Wg[128:,:] + bg); out = E2@Wf+bf
// [R6-proven] concat identity: concat(H,E1)@Wg = U + E1@Wg_bot.
// ---------------------------------------------------------------------------
__global__ __launch_bounds__(256) void k_final2(
    const __bf16* __restrict__ U, const __bf16* __restrict__ E1b,
    const __bf16* __restrict__ WtGb, const float* __restrict__ bg,
    const float* __restrict__ Wf, const float* __restrict__ bf,
    float* __restrict__ out)
{
    __shared__ __bf16 E2s[128][136];

    const int tid  = threadIdx.x;
    const int row0 = blockIdx.x * 128;
    const int wave = tid >> 6, lane = tid & 63;
    const int lm = lane & 15, lq = lane >> 4;

    #pragma unroll
    for (int it = 0; it < 8; ++it) {
        int fid = it * 256 + tid;
        int row = fid >> 4, fr = fid & 15;
        int g = row0 + row; if (g >= L_NODES) g = L_NODES - 1;
        *(bf16x8*)&E2s[row][fr * 8] = *(const bf16x8*)(U + (size_t)g * JDIM + fr * 8);
    }

    bf16x8 aall[2][4];
    #pragma unroll
    for (int t = 0; t < 2; ++t) {
        int grow = row0 + wave * 32 + t * 16 + lm;
        if (grow >= L_NODES) grow = L_NODES - 1;
        const __bf16* ep = E1b + (size_t)grow * JDIM + lq * 8;
        #pragma unroll
        for (int kc = 0; kc < 4; ++kc)
            aall[t][kc] = *(const bf16x8*)(ep + kc * 32);
    }

    const __bf16* bbase = WtGb + (size_t)lm * 128 + lq * 8;
    floatx4 acc[2][8] = {};
    #pragma unroll
    for (int ks = 0; ks < 4; ++ks) {
        bf16x8 bc[8];
        #pragma unroll
        for (int nt = 0; nt < 8; ++nt)
            bc[nt] = *(const bf16x8*)(bbase + (size_t)nt * 16 * 128 + ks * 32);
        #pragma unroll
        for (int t = 0; t < 2; ++t)
            #pragma unroll
            for (int nt = 0; nt < 8; ++nt)
                acc[t][nt] = __builtin_amdgcn_mfma_f32_16x16x32_bf16(
                    aall[t][ks], bc[nt], acc[t][nt], 0, 0, 0);
    }
    __syncthreads();

    #pragma unroll
    for (int nt = 0; nt < 8; ++nt) {
        int col = nt * 16 + lm;
        float bias = bg[col];
        #pragma unroll
        for (int t = 0; t < 2; ++t)
            #pragma unroll
            for (int p = 0; p < 4; ++p) {
                int r = wave * 32 + t * 16 + lq * 4 + p;
                float u = (float)E2s[r][col];
                E2s[r][col] = (__bf16)fmaxf(u + acc[t][nt][p] + bias, 0.f);
            }
    }
    __syncthreads();

    {
        int row = tid >> 1, o = tid & 1;
        int grow = row0 + row;
        if (grow < L_NODES) {
            float a = bf[o];
            #pragma unroll
            for (int j = 0; j < 16; ++j) {
                bf16x8 v = *(bf16x8*)&E2s[row][j * 8];
                #pragma unroll
                for (int c = 0; c < 8; ++c)
                    a = fmaf((float)v[c], Wf[(j * 8 + c) * 2 + o], a);
            }
            out[(size_t)grow * 2 + o] = a;
        }
    }
}

// ---------------------------------------------------------------------------
extern "C" void kernel_launch(void* const* d_in, const int* in_sizes, int n_in,
                              void* d_out, int out_size, void* d_ws, size_t ws_size,
                              hipStream_t stream) {
    const float* X    = (const float*)d_in[0];
    const float* W_h1 = (const float*)d_in[1];
    const float* b_h1 = (const float*)d_in[2];
    const float* W_g1 = (const float*)d_in[3];
    const float* b_g1 = (const float*)d_in[4];
    const float* W_f  = (const float*)d_in[5];
    const float* b_f  = (const float*)d_in[6];
    const int*   idx0 = (const int*)d_in[7];
    const int*   idx1 = (const int*)d_in[8];
    float* out = (float*)d_out;

    // d_ws layout (total 77.0 MB; R1 proved >= 102.4 MB available):
    __bf16* E1b = (__bf16*)d_ws;                          // 25.6 MB
    __bf16* U   = E1b + (size_t)L_NODES * JDIM;           // 25.6 MB (live to end)
    __bf16* V   = U   + (size_t)L_NODES * JDIM;           // 25.6 MB
    __bf16* WtH  = V + (size_t)L_NODES * JDIM;            // 64 KB
    __bf16* WtGu = WtH + 32768;                           // 64 KB
    __bf16* WtGb = WtGu + 32768;                          // 32 KB

    k_prep<<<128, 256, 0, stream>>>(W_h1, W_g1, WtH, WtGu, WtGb);
    k_h1uv<<<(L_NODES + 127) / 128, 256, 0, stream>>>(X, WtH, WtGu, b_h1, U, V);
    k_gather<<<L_NODES / 16, 256, 0, stream>>>(U, V, b_g1, idx0, idx1, E1b);
    k_final2<<<(L_NODES + 127) / 128, 256, 0, stream>>>(U, E1b, WtGb, b_g1, W_f, b_f, out);
}